// Round 1
// baseline (709.162 us; speedup 1.0000x reference)
//
#include <hip/hip_runtime.h>
#include <float.h>
#include <math.h>

#define NN 8192
#define DH 256
#define KNN 10
#define TSTEPS 10
#define EPSC 0.1f

typedef short s8v __attribute__((ext_vector_type(8)));
typedef float f4v __attribute__((ext_vector_type(4)));

__device__ __forceinline__ float bf2f(unsigned short u) {
    union { unsigned u; float f; } c; c.u = ((unsigned)u) << 16; return c.f;
}
__device__ __forceinline__ unsigned short f2bf(float f) {
    union { float f; unsigned u; } c; c.f = f;
    unsigned r = c.u + 0x7FFF + ((c.u >> 16) & 1);
    return (unsigned short)(r >> 16);
}

// ---------------- Kernel 1: conv_ws [3][256][256] (k,n) -> bf16 Wt [3][n][k] ----
__global__ void prep_wt(const float* __restrict__ W, unsigned short* __restrict__ Wt) {
    int e = blockIdx.x * 256 + threadIdx.x;     // 0 .. 3*65536-1
    int g = e >> 16; int rem = e & 65535;
    int n = rem >> 8; int k = rem & 255;
    Wt[e] = f2bf(W[g * 65536 + k * 256 + n]);
}

// ---------------- Kernel 2: kNN (k=10, no self) -------------------------------
__global__ void knn_kernel(const float* __restrict__ pos, int* __restrict__ nbr) {
    __shared__ float cv[256 * KNN];
    __shared__ int   ci[256 * KNN];
    __shared__ float rv[4]; __shared__ int rj[4]; __shared__ int rs[4];
    int i = blockIdx.x, tid = threadIdx.x;
    float xi = pos[i * 3], yi = pos[i * 3 + 1], zi = pos[i * 3 + 2];
    float sqi = xi * xi + yi * yi + zi * zi;
    float bd[KNN]; int bi[KNN];
    for (int q = 0; q < KNN; q++) { bd[q] = FLT_MAX; bi[q] = -1; }
    for (int j = tid; j < NN; j += 256) {
        float xj = pos[j * 3], yj = pos[j * 3 + 1], zj = pos[j * 3 + 2];
        float m = xj * xi + yj * yi + zj * zi;
        float sqj = xj * xj + yj * yj + zj * zj;
        float d = (sqi + sqj) - 2.0f * m;
        if (j == i) d = FLT_MAX;
        if (d < bd[KNN - 1]) {
            int q = KNN - 1;
            while (q > 0 && bd[q - 1] > d) { bd[q] = bd[q - 1]; bi[q] = bi[q - 1]; q--; }
            bd[q] = d; bi[q] = j;
        }
    }
    for (int q = 0; q < KNN; q++) { cv[tid * KNN + q] = bd[q]; ci[tid * KNN + q] = bi[q]; }
    __syncthreads();
    for (int r = 0; r < KNN; r++) {
        float v = FLT_MAX; int jj = 0x7fffffff; int slot = -1;
        for (int q = 0; q < KNN; q++) {
            float c = cv[tid * KNN + q]; int cj = ci[tid * KNN + q];
            if (c < v || (c == v && cj < jj)) { v = c; jj = cj; slot = tid * KNN + q; }
        }
        for (int off = 32; off; off >>= 1) {
            float ov = __shfl_down(v, off, 64);
            int oj = __shfl_down(jj, off, 64);
            int os = __shfl_down(slot, off, 64);
            if (ov < v || (ov == v && oj < jj)) { v = ov; jj = oj; slot = os; }
        }
        int lane = tid & 63, wid = tid >> 6;
        if (lane == 0) { rv[wid] = v; rj[wid] = jj; rs[wid] = slot; }
        __syncthreads();
        if (tid == 0) {
            float bv = rv[0]; int bj = rj[0], bs = rs[0];
            for (int wq = 1; wq < 4; wq++)
                if (rv[wq] < bv || (rv[wq] == bv && rj[wq] < bj)) { bv = rv[wq]; bj = rj[wq]; bs = rs[wq]; }
            nbr[i * KNN + r] = bj;
            cv[bs] = FLT_MAX;
        }
        __syncthreads();
    }
}

// ---------------- Kernel 3: h = lm@emb_w + emb_b ; x = h@rw + rb --------------
__global__ void emb_kernel(const float* __restrict__ lm, const float* __restrict__ ew,
                           const float* __restrict__ eb, const float* __restrict__ rw,
                           const float* __restrict__ rb,
                           float* __restrict__ hdo, unsigned short* __restrict__ hbf,
                           float* __restrict__ xout) {
    __shared__ float s0[4], s1[4], s2[4];
    int i = blockIdx.x, d = threadIdx.x;
    float a0 = lm[i * 3], a1 = lm[i * 3 + 1], a2 = lm[i * 3 + 2];
    float h = eb[d] + a0 * ew[d] + a1 * ew[256 + d] + a2 * ew[512 + d];
    hdo[i * 256 + d] = h;
    hbf[i * 256 + d] = f2bf(h);
    float p0 = h * rw[d * 3], p1 = h * rw[d * 3 + 1], p2 = h * rw[d * 3 + 2];
    for (int off = 32; off; off >>= 1) {
        p0 += __shfl_down(p0, off, 64);
        p1 += __shfl_down(p1, off, 64);
        p2 += __shfl_down(p2, off, 64);
    }
    int lane = d & 63, wid = d >> 6;
    if (lane == 0) { s0[wid] = p0; s1[wid] = p1; s2[wid] = p2; }
    __syncthreads();
    if (d == 0) {
        xout[i * 3 + 0] = s0[0] + s0[1] + s0[2] + s0[3] + rb[0];
        xout[i * 3 + 1] = s1[0] + s1[1] + s1[2] + s1[3] + rb[1];
        xout[i * 3 + 2] = s2[0] + s2[1] + s2[2] + s2[3] + rb[2];
    }
}

// ---------------- Kernel 4: dst[i] = 0.1 * sum_{j in nbr(i)} src[j] (bf16) ----
__global__ void agg_kernel(const unsigned short* __restrict__ src,
                           unsigned short* __restrict__ dst,
                           const int* __restrict__ nbr) {
    int tid = threadIdx.x;
    int wid = tid >> 6, lane = tid & 63;
    int node = blockIdx.x * 4 + wid;
    int d0 = lane * 4;
    float a0 = 0.f, a1 = 0.f, a2 = 0.f, a3 = 0.f;
    const int* nb = nbr + node * KNN;
    for (int q = 0; q < KNN; q++) {
        int j = nb[q];
        uint2 v = *(const uint2*)(src + j * 256 + d0);
        a0 += bf2f((unsigned short)(v.x & 0xffff));
        a1 += bf2f((unsigned short)(v.x >> 16));
        a2 += bf2f((unsigned short)(v.y & 0xffff));
        a3 += bf2f((unsigned short)(v.y >> 16));
    }
    uint2 o;
    o.x = (unsigned)f2bf(a0 * 0.1f) | ((unsigned)f2bf(a1 * 0.1f) << 16);
    o.y = (unsigned)f2bf(a2 * 0.1f) | ((unsigned)f2bf(a3 * 0.1f) << 16);
    *(uint2*)(dst + node * 256 + d0) = o;
}

// ---------------- Kernel 5: fused GEMM + Euler update + readout ---------------
// c = h@W0 + x1@W1 + x2@W2 + cb ; h += 0.1*tanh(c) ; y = h@rw + rb
__launch_bounds__(256)
__global__ void gemm_step(unsigned short* hbf,                      // bf16 h (read k<256, write epilogue)
                          const unsigned short* __restrict__ x1,
                          const unsigned short* __restrict__ x2,
                          const unsigned short* __restrict__ Wt,    // [3][n][k] bf16
                          const float* __restrict__ cb,
                          const float* __restrict__ rw, const float* __restrict__ rb,
                          float* hdo,                               // fp32 master h (d_out h slot)
                          float* __restrict__ yout,                 // land_pred[t]
                          float* yfin)                              // d_out y slot or null
{
    __shared__ __align__(16) short Al[32 * 72];    // rows 0..31, stride 72 (+8 pad)
    __shared__ __align__(16) short Bl[256 * 72];   // n 0..255, stride 72
    __shared__ float rwl[768];
    __shared__ float cbl[256];
    __shared__ float yred[2][2][4][4][3];

    int tid = threadIdx.x;
    int m0 = blockIdx.x * 32;
    for (int idx = tid; idx < 768; idx += 256) rwl[idx] = rw[idx];
    cbl[tid] = cb[tid];

    f4v acc[8];
    for (int f = 0; f < 8; f++) acc[f] = (f4v){0.f, 0.f, 0.f, 0.f};

    int w = tid >> 6, lane = tid & 63;
    int rowgrp = w & 1, nhalf = w >> 1;
    int quad = lane >> 4, l15 = lane & 15;

    for (int kc = 0; kc < 12; kc++) {
        int kb = kc * 64;
        const unsigned short* asrc = (kb < 256) ? (const unsigned short*)hbf
                                   : (kb < 512) ? x1 : x2;
        int klocal = kb & 255;
        // stage A tile: 32 rows x 64 k  (one uint4 = 8 bf16 per thread)
        {
            int row = tid >> 3, c8 = (tid & 7) * 8;
            uint4 v = *(const uint4*)(asrc + (m0 + row) * 256 + klocal + c8);
            *(uint4*)(&Al[row * 72 + c8]) = v;
        }
        // stage B tile: 256 n x 64 k
        {
            const unsigned short* bsrc = Wt + (kb >> 8) * 65536;
            int c8 = (tid & 7) * 8, rbase = tid >> 3;
            for (int r2 = 0; r2 < 8; r2++) {
                int n = r2 * 32 + rbase;
                uint4 v = *(const uint4*)(bsrc + n * 256 + klocal + c8);
                *(uint4*)(&Bl[n * 72 + c8]) = v;
            }
        }
        __syncthreads();
        for (int ks = 0; ks < 2; ks++) {
            s8v a = *(const s8v*)(&Al[(rowgrp * 16 + l15) * 72 + ks * 32 + quad * 8]);
            for (int f = 0; f < 8; f++) {
                int n = nhalf * 128 + f * 16 + l15;
                s8v b = *(const s8v*)(&Bl[n * 72 + ks * 32 + quad * 8]);
                acc[f] = __builtin_amdgcn_mfma_f32_16x16x32_bf16(a, b, acc[f], 0, 0, 0);
            }
        }
        __syncthreads();
    }

    // epilogue: bias, tanh, Euler step, bf16 refresh, partial readout
    float py[4][3] = {};
    for (int f = 0; f < 8; f++) {
        int col = nhalf * 128 + f * 16 + l15;
        float cbv = cbl[col];
        float rw0 = rwl[col * 3], rw1 = rwl[col * 3 + 1], rw2 = rwl[col * 3 + 2];
        for (int r = 0; r < 4; r++) {
            int grow = m0 + rowgrp * 16 + quad * 4 + r;
            float cval = acc[f][r] + cbv;
            float hn = hdo[grow * 256 + col] + EPSC * tanhf(cval);
            hdo[grow * 256 + col] = hn;
            hbf[grow * 256 + col] = f2bf(hn);
            py[r][0] += hn * rw0; py[r][1] += hn * rw1; py[r][2] += hn * rw2;
        }
    }
    // reduce over the 16 lanes of each quad (cols within this wave's half)
    for (int off = 1; off < 16; off <<= 1)
        for (int r = 0; r < 4; r++)
            for (int j = 0; j < 3; j++)
                py[r][j] += __shfl_xor(py[r][j], off, 64);
    if (l15 == 0)
        for (int r = 0; r < 4; r++)
            for (int j = 0; j < 3; j++)
                yred[rowgrp][nhalf][quad][r][j] = py[r][j];
    __syncthreads();
    if (nhalf == 0 && l15 == 0) {
        for (int r = 0; r < 4; r++) {
            int grow = m0 + rowgrp * 16 + quad * 4 + r;
            for (int j = 0; j < 3; j++) {
                float yv = yred[rowgrp][0][quad][r][j] + yred[rowgrp][1][quad][r][j] + rb[j];
                yout[grow * 3 + j] = yv;
                if (yfin) yfin[grow * 3 + j] = yv;
            }
        }
    }
}

extern "C" void kernel_launch(void* const* d_in, const int* in_sizes, int n_in,
                              void* d_out, int out_size, void* d_ws, size_t ws_size,
                              hipStream_t stream) {
    const float* lm = (const float*)d_in[0];   // [8192,3]
    const float* ew = (const float*)d_in[1];   // [3,256]
    const float* eb = (const float*)d_in[2];   // [256]
    const float* rw = (const float*)d_in[3];   // [256,3]
    const float* rb = (const float*)d_in[4];   // [3]
    const float* cw = (const float*)d_in[5];   // [3,256,256]
    const float* cb = (const float*)d_in[6];   // [256]

    float* out = (float*)d_out;
    float* y_out = out;                              // 8192*3
    float* h_out = out + 24576;                      // 8192*256 (also fp32 working h)
    float* x_out = out + 24576 + 2097152;            // 8192*3
    float* lp_out = x_out + 24576;                   // 10*8192*3

    char* ws = (char*)d_ws;
    int* nbr = (int*)ws;                 ws += NN * KNN * sizeof(int);
    unsigned short* hbf = (unsigned short*)ws; ws += NN * DH * 2;
    unsigned short* x1  = (unsigned short*)ws; ws += NN * DH * 2;
    unsigned short* x2  = (unsigned short*)ws; ws += NN * DH * 2;
    unsigned short* Wt  = (unsigned short*)ws; ws += 3 * DH * DH * 2;

    prep_wt<<<768, 256, 0, stream>>>(cw, Wt);
    knn_kernel<<<NN, 256, 0, stream>>>(lm, nbr);
    emb_kernel<<<NN, 256, 0, stream>>>(lm, ew, eb, rw, rb, h_out, hbf, x_out);
    for (int t = 0; t < TSTEPS; t++) {
        agg_kernel<<<NN / 4, 256, 0, stream>>>(hbf, x1, nbr);
        agg_kernel<<<NN / 4, 256, 0, stream>>>(x1, x2, nbr);
        gemm_step<<<NN / 32, 256, 0, stream>>>(hbf, x1, x2, Wt, cb, rw, rb, h_out,
                                               lp_out + t * 24576,
                                               (t == TSTEPS - 1) ? y_out : nullptr);
    }
}

// Round 2
// 618.307 us; speedup vs baseline: 1.1469x; 1.1469x over previous
//
#include <hip/hip_runtime.h>
#include <float.h>
#include <math.h>

#define NN 8192
#define DH 256
#define KNN 10
#define TSTEPS 10
#define EPSC 0.1f
#define NSEG 16
#define SEGSZ (NN / NSEG)   // 512

typedef short s8v __attribute__((ext_vector_type(8)));
typedef float f4v __attribute__((ext_vector_type(4)));

__device__ __forceinline__ float bf2f(unsigned short u) {
    union { unsigned u; float f; } c; c.u = ((unsigned)u) << 16; return c.f;
}
__device__ __forceinline__ unsigned short f2bf(float f) {
    union { float f; unsigned u; } c; c.f = f;
    unsigned r = c.u + 0x7FFF + ((c.u >> 16) & 1);
    return (unsigned short)(r >> 16);
}

// ---------------- conv_ws [3][256][256] (k,n) -> bf16 Wt [3][n][k] ------------
__global__ void prep_wt(const float* __restrict__ W, unsigned short* __restrict__ Wt) {
    int e = blockIdx.x * 256 + threadIdx.x;
    int g = e >> 16; int rem = e & 65535;
    int n = rem >> 8; int k = rem & 255;
    Wt[e] = f2bf(W[g * 65536 + k * 256 + n]);
}

// ---------------- pos4[j] = {x, y, z, |p|^2} ----------------------------------
__global__ void prep_pos(const float* __restrict__ pos, float4* __restrict__ pos4) {
    int j = blockIdx.x * 256 + threadIdx.x;
    float x = pos[j * 3], y = pos[j * 3 + 1], z = pos[j * 3 + 2];
    float4 v; v.x = x; v.y = y; v.z = z; v.w = x * x + y * y + z * z;
    pos4[j] = v;
}

// ---------------- kNN pass 1: per-(query, segment) top-10 ---------------------
// grid = 32 qblocks * 16 segs; thread t owns query qb*256+t, scans 512 candidates.
// Register-resident sorted top-10 (ascending); fully-unrolled bubble insert.
__launch_bounds__(256)
__global__ void knn_scan(const float* __restrict__ pos, const float4* __restrict__ pos4,
                         float* __restrict__ segd, int* __restrict__ segi) {
    __shared__ float4 cand[SEGSZ];
    int qb = blockIdx.x >> 4, seg = blockIdx.x & 15;
    int tid = threadIdx.x;
    int i = qb * 256 + tid;
    for (int t = tid; t < SEGSZ; t += 256) cand[t] = pos4[seg * SEGSZ + t];
    float xi = pos[i * 3], yi = pos[i * 3 + 1], zi = pos[i * 3 + 2];
    float sqi = xi * xi + yi * yi + zi * zi;
    __syncthreads();

    float bd[KNN]; int bi[KNN];
#pragma unroll
    for (int q = 0; q < KNN; q++) { bd[q] = FLT_MAX; bi[q] = -1; }

    int jbase = seg * SEGSZ;
    for (int t = 0; t < SEGSZ; t++) {
        float4 c = cand[t];
        float m = c.x * xi + c.y * yi + c.z * zi;
        float d = (sqi + c.w) - 2.0f * m;
        int j = jbase + t;
        if (j == i) d = FLT_MAX;
        if (d < bd[KNN - 1]) {
            float cd = d; int cj = j;
#pragma unroll
            for (int q = 0; q < KNN; q++) {
                bool sw = cd < bd[q];
                float nd = sw ? cd : bd[q]; int ni = sw ? cj : bi[q];
                float xd = sw ? bd[q] : cd; int xj = sw ? bi[q] : cj;
                bd[q] = nd; bi[q] = ni; cd = xd; cj = xj;
            }
        }
    }
    float* dp = segd + (seg * NN + i) * KNN;
    int*   ip = segi + (seg * NN + i) * KNN;
#pragma unroll
    for (int q = 0; q < KNN; q++) { dp[q] = bd[q]; ip[q] = bi[q]; }
}

// ---------------- kNN pass 2: merge 16 sorted lists -> final top-10 -----------
__global__ void knn_merge(const float* __restrict__ segd, const int* __restrict__ segi,
                          int* __restrict__ nbr) {
    int i = blockIdx.x * 256 + threadIdx.x;
    float bd[KNN]; int bi[KNN];
#pragma unroll
    for (int q = 0; q < KNN; q++) { bd[q] = FLT_MAX; bi[q] = -1; }
    for (int s = 0; s < NSEG; s++) {
        const float* dp = segd + (s * NN + i) * KNN;
        const int*   ip = segi + (s * NN + i) * KNN;
#pragma unroll
        for (int q = 0; q < KNN; q++) {
            float d = dp[q]; int j = ip[q];
            if (d < bd[KNN - 1]) {
                float cd = d; int cj = j;
#pragma unroll
                for (int p = 0; p < KNN; p++) {
                    bool sw = cd < bd[p];
                    float nd = sw ? cd : bd[p]; int ni = sw ? cj : bi[p];
                    float xd = sw ? bd[p] : cd; int xj = sw ? bi[p] : cj;
                    bd[p] = nd; bi[p] = ni; cd = xd; cj = xj;
                }
            }
        }
    }
#pragma unroll
    for (int q = 0; q < KNN; q++) nbr[i * KNN + q] = bi[q];
}

// ---------------- h = lm@emb_w + emb_b ; x = h@rw + rb ------------------------
__global__ void emb_kernel(const float* __restrict__ lm, const float* __restrict__ ew,
                           const float* __restrict__ eb, const float* __restrict__ rw,
                           const float* __restrict__ rb,
                           float* __restrict__ hdo, unsigned short* __restrict__ hbf,
                           float* __restrict__ xout) {
    __shared__ float s0[4], s1[4], s2[4];
    int i = blockIdx.x, d = threadIdx.x;
    float a0 = lm[i * 3], a1 = lm[i * 3 + 1], a2 = lm[i * 3 + 2];
    float h = eb[d] + a0 * ew[d] + a1 * ew[256 + d] + a2 * ew[512 + d];
    hdo[i * 256 + d] = h;
    hbf[i * 256 + d] = f2bf(h);
    float p0 = h * rw[d * 3], p1 = h * rw[d * 3 + 1], p2 = h * rw[d * 3 + 2];
    for (int off = 32; off; off >>= 1) {
        p0 += __shfl_down(p0, off, 64);
        p1 += __shfl_down(p1, off, 64);
        p2 += __shfl_down(p2, off, 64);
    }
    int lane = d & 63, wid = d >> 6;
    if (lane == 0) { s0[wid] = p0; s1[wid] = p1; s2[wid] = p2; }
    __syncthreads();
    if (d == 0) {
        xout[i * 3 + 0] = s0[0] + s0[1] + s0[2] + s0[3] + rb[0];
        xout[i * 3 + 1] = s1[0] + s1[1] + s1[2] + s1[3] + rb[1];
        xout[i * 3 + 2] = s2[0] + s2[1] + s2[2] + s2[3] + rb[2];
    }
}

// ---------------- dst[i] = 0.1 * sum_{j in nbr(i)} src[j] (bf16) --------------
__global__ void agg_kernel(const unsigned short* __restrict__ src,
                           unsigned short* __restrict__ dst,
                           const int* __restrict__ nbr) {
    int tid = threadIdx.x;
    int wid = tid >> 6, lane = tid & 63;
    int node = blockIdx.x * 4 + wid;
    int d0 = lane * 4;
    float a0 = 0.f, a1 = 0.f, a2 = 0.f, a3 = 0.f;
    const int* nb = nbr + node * KNN;
    for (int q = 0; q < KNN; q++) {
        int j = nb[q];
        uint2 v = *(const uint2*)(src + j * 256 + d0);
        a0 += bf2f((unsigned short)(v.x & 0xffff));
        a1 += bf2f((unsigned short)(v.x >> 16));
        a2 += bf2f((unsigned short)(v.y & 0xffff));
        a3 += bf2f((unsigned short)(v.y >> 16));
    }
    uint2 o;
    o.x = (unsigned)f2bf(a0 * 0.1f) | ((unsigned)f2bf(a1 * 0.1f) << 16);
    o.y = (unsigned)f2bf(a2 * 0.1f) | ((unsigned)f2bf(a3 * 0.1f) << 16);
    *(uint2*)(dst + node * 256 + d0) = o;
}

// ---------------- fused GEMM + Euler update + readout -------------------------
__launch_bounds__(256)
__global__ void gemm_step(unsigned short* hbf,
                          const unsigned short* __restrict__ x1,
                          const unsigned short* __restrict__ x2,
                          const unsigned short* __restrict__ Wt,
                          const float* __restrict__ cb,
                          const float* __restrict__ rw, const float* __restrict__ rb,
                          float* hdo, float* __restrict__ yout, float* yfin) {
    __shared__ __align__(16) short Al[32 * 72];
    __shared__ __align__(16) short Bl[256 * 72];
    __shared__ float rwl[768];
    __shared__ float cbl[256];
    __shared__ float yred[2][2][4][4][3];

    int tid = threadIdx.x;
    int m0 = blockIdx.x * 32;
    for (int idx = tid; idx < 768; idx += 256) rwl[idx] = rw[idx];
    cbl[tid] = cb[tid];

    f4v acc[8];
    for (int f = 0; f < 8; f++) acc[f] = (f4v){0.f, 0.f, 0.f, 0.f};

    int w = tid >> 6, lane = tid & 63;
    int rowgrp = w & 1, nhalf = w >> 1;
    int quad = lane >> 4, l15 = lane & 15;

    for (int kc = 0; kc < 12; kc++) {
        int kb = kc * 64;
        const unsigned short* asrc = (kb < 256) ? (const unsigned short*)hbf
                                   : (kb < 512) ? x1 : x2;
        int klocal = kb & 255;
        {
            int row = tid >> 3, c8 = (tid & 7) * 8;
            uint4 v = *(const uint4*)(asrc + (m0 + row) * 256 + klocal + c8);
            *(uint4*)(&Al[row * 72 + c8]) = v;
        }
        {
            const unsigned short* bsrc = Wt + (kb >> 8) * 65536;
            int c8 = (tid & 7) * 8, rbase = tid >> 3;
            for (int r2 = 0; r2 < 8; r2++) {
                int n = r2 * 32 + rbase;
                uint4 v = *(const uint4*)(bsrc + n * 256 + klocal + c8);
                *(uint4*)(&Bl[n * 72 + c8]) = v;
            }
        }
        __syncthreads();
        for (int ks = 0; ks < 2; ks++) {
            s8v a = *(const s8v*)(&Al[(rowgrp * 16 + l15) * 72 + ks * 32 + quad * 8]);
            for (int f = 0; f < 8; f++) {
                int n = nhalf * 128 + f * 16 + l15;
                s8v b = *(const s8v*)(&Bl[n * 72 + ks * 32 + quad * 8]);
                acc[f] = __builtin_amdgcn_mfma_f32_16x16x32_bf16(a, b, acc[f], 0, 0, 0);
            }
        }
        __syncthreads();
    }

    float py[4][3] = {};
    for (int f = 0; f < 8; f++) {
        int col = nhalf * 128 + f * 16 + l15;
        float cbv = cbl[col];
        float rw0 = rwl[col * 3], rw1 = rwl[col * 3 + 1], rw2 = rwl[col * 3 + 2];
        for (int r = 0; r < 4; r++) {
            int grow = m0 + rowgrp * 16 + quad * 4 + r;
            float cval = acc[f][r] + cbv;
            float hn = hdo[grow * 256 + col] + EPSC * tanhf(cval);
            hdo[grow * 256 + col] = hn;
            hbf[grow * 256 + col] = f2bf(hn);
            py[r][0] += hn * rw0; py[r][1] += hn * rw1; py[r][2] += hn * rw2;
        }
    }
    for (int off = 1; off < 16; off <<= 1)
        for (int r = 0; r < 4; r++)
            for (int j = 0; j < 3; j++)
                py[r][j] += __shfl_xor(py[r][j], off, 64);
    if (l15 == 0)
        for (int r = 0; r < 4; r++)
            for (int j = 0; j < 3; j++)
                yred[rowgrp][nhalf][quad][r][j] = py[r][j];
    __syncthreads();
    if (nhalf == 0 && l15 == 0) {
        for (int r = 0; r < 4; r++) {
            int grow = m0 + rowgrp * 16 + quad * 4 + r;
            for (int j = 0; j < 3; j++) {
                float yv = yred[rowgrp][0][quad][r][j] + yred[rowgrp][1][quad][r][j] + rb[j];
                yout[grow * 3 + j] = yv;
                if (yfin) yfin[grow * 3 + j] = yv;
            }
        }
    }
}

extern "C" void kernel_launch(void* const* d_in, const int* in_sizes, int n_in,
                              void* d_out, int out_size, void* d_ws, size_t ws_size,
                              hipStream_t stream) {
    const float* lm = (const float*)d_in[0];
    const float* ew = (const float*)d_in[1];
    const float* eb = (const float*)d_in[2];
    const float* rw = (const float*)d_in[3];
    const float* rb = (const float*)d_in[4];
    const float* cw = (const float*)d_in[5];
    const float* cb = (const float*)d_in[6];

    float* out = (float*)d_out;
    float* y_out = out;
    float* h_out = out + 24576;
    float* x_out = out + 24576 + 2097152;
    float* lp_out = x_out + 24576;

    char* ws = (char*)d_ws;
    int* nbr = (int*)ws;                       ws += NN * KNN * sizeof(int);      // 328 KB
    float4* pos4 = (float4*)ws;                ws += NN * sizeof(float4);         // 128 KB
    // union region: {segd, segi} (kNN scratch) aliases {hbf, x1, x2, Wt} (sim scratch)
    char* uni = ws;
    float* segd = (float*)uni;                                                   // 5.24 MB
    int*   segi = (int*)(uni + NSEG * NN * KNN * sizeof(float));                 // 5.24 MB
    unsigned short* hbf = (unsigned short*)uni;
    unsigned short* x1  = hbf + NN * DH;
    unsigned short* x2  = x1 + NN * DH;
    unsigned short* Wt  = x2 + NN * DH;

    prep_pos<<<NN / 256, 256, 0, stream>>>(lm, pos4);
    knn_scan<<<32 * NSEG, 256, 0, stream>>>(lm, pos4, segd, segi);
    knn_merge<<<NN / 256, 256, 0, stream>>>(segd, segi, nbr);
    prep_wt<<<768, 256, 0, stream>>>(cw, Wt);
    emb_kernel<<<NN, 256, 0, stream>>>(lm, ew, eb, rw, rb, h_out, hbf, x_out);
    for (int t = 0; t < TSTEPS; t++) {
        agg_kernel<<<NN / 4, 256, 0, stream>>>(hbf, x1, nbr);
        agg_kernel<<<NN / 4, 256, 0, stream>>>(x1, x2, nbr);
        gemm_step<<<NN / 32, 256, 0, stream>>>(hbf, x1, x2, Wt, cb, rw, rb, h_out,
                                               lp_out + t * 24576,
                                               (t == TSTEPS - 1) ? y_out : nullptr);
    }
}

// Round 3
// 569.902 us; speedup vs baseline: 1.2444x; 1.0849x over previous
//
#include <hip/hip_runtime.h>
#include <float.h>
#include <math.h>

#define NN 8192
#define DH 256
#define KNN 10
#define TSTEPS 10
#define EPSC 0.1f
#define NSEG 16
#define SEGSZ (NN / NSEG)   // 512

typedef short s8v __attribute__((ext_vector_type(8)));
typedef float f4v __attribute__((ext_vector_type(4)));

__device__ __forceinline__ float bf2f(unsigned short u) {
    union { unsigned u; float f; } c; c.u = ((unsigned)u) << 16; return c.f;
}
__device__ __forceinline__ unsigned short f2bf(float f) {
    union { float f; unsigned u; } c; c.f = f;
    unsigned r = c.u + 0x7FFF + ((c.u >> 16) & 1);
    return (unsigned short)(r >> 16);
}

// Rank-parallel top-10 insert: flags independent, selects depth ~3 (no serial chain).
// Strict '<' keeps earlier (= lower-index) entries on ties, matching top_k stability.
__device__ __forceinline__ void ins10(float (&bd)[KNN], int (&bi)[KNN], float d, int j) {
    bool c[KNN];
#pragma unroll
    for (int q = 0; q < KNN; q++) c[q] = d < bd[q];
#pragma unroll
    for (int q = KNN - 1; q > 0; q--) {
        bd[q] = c[q] ? (c[q - 1] ? bd[q - 1] : d) : bd[q];
        bi[q] = c[q] ? (c[q - 1] ? bi[q - 1] : j) : bi[q];
    }
    bd[0] = c[0] ? d : bd[0];
    bi[0] = c[0] ? j : bi[0];
}

// ---------------- conv_ws [3][256][256] (k,n) -> bf16 Wt [3][n][k] ------------
__global__ void prep_wt(const float* __restrict__ W, unsigned short* __restrict__ Wt) {
    int e = blockIdx.x * 256 + threadIdx.x;
    int g = e >> 16; int rem = e & 65535;
    int n = rem >> 8; int k = rem & 255;
    Wt[e] = f2bf(W[g * 65536 + k * 256 + n]);
}

// ---------------- pos4[j] = {x, y, z, |p|^2} ----------------------------------
__global__ void prep_pos(const float* __restrict__ pos, float4* __restrict__ pos4) {
    int j = blockIdx.x * 256 + threadIdx.x;
    float x = pos[j * 3], y = pos[j * 3 + 1], z = pos[j * 3 + 2];
    float4 v; v.x = x; v.y = y; v.z = z; v.w = x * x + y * y + z * z;
    pos4[j] = v;
}

// ---------------- kNN pass 1: per-(query, segment) top-10 ---------------------
__launch_bounds__(256)
__global__ void knn_scan(const float* __restrict__ pos, const float4* __restrict__ pos4,
                         uint2* __restrict__ segdj) {
    __shared__ float4 cand[SEGSZ];
    int qb = blockIdx.x >> 4, seg = blockIdx.x & 15;
    int tid = threadIdx.x;
    int i = qb * 256 + tid;
    for (int t = tid; t < SEGSZ; t += 256) cand[t] = pos4[seg * SEGSZ + t];
    float xi = pos[i * 3], yi = pos[i * 3 + 1], zi = pos[i * 3 + 2];
    float sqi = xi * xi + yi * yi + zi * zi;
    __syncthreads();

    float bd[KNN]; int bi[KNN];
#pragma unroll
    for (int q = 0; q < KNN; q++) { bd[q] = FLT_MAX; bi[q] = -1; }

    int jbase = seg * SEGSZ;
#pragma unroll 4
    for (int t = 0; t < SEGSZ; t++) {
        float4 c = cand[t];
        float m = c.x * xi + c.y * yi + c.z * zi;
        float d = (sqi + c.w) - 2.0f * m;
        int j = jbase + t;
        if (j == i) d = FLT_MAX;          // folds to cmp+cndmask
        ins10(bd, bi, d, j);              // unconditional, branchless
    }
    uint2* op = segdj + (seg * NN + i) * KNN;
#pragma unroll
    for (int q = 0; q < KNN; q++) {
        uint2 v; v.x = __float_as_uint(bd[q]); v.y = (unsigned)bi[q];
        op[q] = v;
    }
}

// ---------------- kNN pass 2: merge 16 sorted lists -> final top-10 -----------
__global__ void knn_merge(const uint2* __restrict__ segdj, int* __restrict__ nbr) {
    int i = blockIdx.x * 256 + threadIdx.x;
    float bd[KNN]; int bi[KNN];
#pragma unroll
    for (int q = 0; q < KNN; q++) { bd[q] = FLT_MAX; bi[q] = -1; }
    for (int s = 0; s < NSEG; s++) {       // ascending seg = ascending index on ties
        const uint2* p = segdj + (s * NN + i) * KNN;
#pragma unroll
        for (int q = 0; q < KNN; q++) {
            uint2 v = p[q];
            ins10(bd, bi, __uint_as_float(v.x), (int)v.y);
        }
    }
#pragma unroll
    for (int q = 0; q < KNN; q++) nbr[i * KNN + q] = bi[q];
}

// ---------------- h = lm@emb_w + emb_b ; x = h@rw + rb ------------------------
__global__ void emb_kernel(const float* __restrict__ lm, const float* __restrict__ ew,
                           const float* __restrict__ eb, const float* __restrict__ rw,
                           const float* __restrict__ rb,
                           float* __restrict__ hdo, unsigned short* __restrict__ hbf,
                           float* __restrict__ xout) {
    __shared__ float s0[4], s1[4], s2[4];
    int i = blockIdx.x, d = threadIdx.x;
    float a0 = lm[i * 3], a1 = lm[i * 3 + 1], a2 = lm[i * 3 + 2];
    float h = eb[d] + a0 * ew[d] + a1 * ew[256 + d] + a2 * ew[512 + d];
    hdo[i * 256 + d] = h;
    hbf[i * 256 + d] = f2bf(h);
    float p0 = h * rw[d * 3], p1 = h * rw[d * 3 + 1], p2 = h * rw[d * 3 + 2];
    for (int off = 32; off; off >>= 1) {
        p0 += __shfl_down(p0, off, 64);
        p1 += __shfl_down(p1, off, 64);
        p2 += __shfl_down(p2, off, 64);
    }
    int lane = d & 63, wid = d >> 6;
    if (lane == 0) { s0[wid] = p0; s1[wid] = p1; s2[wid] = p2; }
    __syncthreads();
    if (d == 0) {
        xout[i * 3 + 0] = s0[0] + s0[1] + s0[2] + s0[3] + rb[0];
        xout[i * 3 + 1] = s1[0] + s1[1] + s1[2] + s1[3] + rb[1];
        xout[i * 3 + 2] = s2[0] + s2[1] + s2[2] + s2[3] + rb[2];
    }
}

// ---------------- hop-1: x1[i] = 0.1 * sum_{j in nbr(i)} hbf[j] ---------------
__global__ void agg_kernel(const unsigned short* __restrict__ src,
                           unsigned short* __restrict__ dst,
                           const int* __restrict__ nbr) {
    int tid = threadIdx.x;
    int wid = tid >> 6, lane = tid & 63;
    int node = blockIdx.x * 4 + wid;
    int d0 = lane * 4;
    float a0 = 0.f, a1 = 0.f, a2 = 0.f, a3 = 0.f;
    const int* nb = nbr + node * KNN;
    for (int q = 0; q < KNN; q++) {
        int j = nb[q];
        uint2 v = *(const uint2*)(src + j * 256 + d0);
        a0 += bf2f((unsigned short)(v.x & 0xffff));
        a1 += bf2f((unsigned short)(v.x >> 16));
        a2 += bf2f((unsigned short)(v.y & 0xffff));
        a3 += bf2f((unsigned short)(v.y >> 16));
    }
    uint2 o;
    o.x = (unsigned)f2bf(a0 * 0.1f) | ((unsigned)f2bf(a1 * 0.1f) << 16);
    o.y = (unsigned)f2bf(a2 * 0.1f) | ((unsigned)f2bf(a3 * 0.1f) << 16);
    *(uint2*)(dst + node * 256 + d0) = o;
}

// ------- fused: hop-2 gather (x2 tile in LDS) + GEMM + Euler + readout --------
__launch_bounds__(256)
__global__ void gemm_step(unsigned short* hbf,
                          const unsigned short* __restrict__ x1,
                          const int* __restrict__ nbr,
                          const unsigned short* __restrict__ Wt,
                          const float* __restrict__ cb,
                          const float* __restrict__ rw, const float* __restrict__ rb,
                          float* hdo, float* __restrict__ yout, float* yfin) {
    __shared__ __align__(16) short Al[32 * 72];
    __shared__ __align__(16) short Bl[256 * 72];
    __shared__ __align__(16) short X2[32 * 264];   // x2 tile, stride 264 (132 dw -> 2-way max)
    __shared__ float rwl[768];
    __shared__ float cbl[256];
    __shared__ float yred[2][2][4][4][3];

    int tid = threadIdx.x;
    int m0 = blockIdx.x * 32;
    for (int idx = tid; idx < 768; idx += 256) rwl[idx] = rw[idx];
    cbl[tid] = cb[tid];

    // ---- fused hop-2 aggregation: X2[row][:] = bf16(0.1 * sum x1[nbr[row]]) ----
    {
        int row = tid >> 3, cg = tid & 7;          // 32 rows x 8 col-groups of 32
        const int* nb = nbr + (m0 + row) * KNN;
        float a[32];
#pragma unroll
        for (int e = 0; e < 32; e++) a[e] = 0.f;
        for (int q = 0; q < KNN; q++) {
            int j = nb[q];
            const uint4* p = (const uint4*)(x1 + j * 256 + cg * 32);
#pragma unroll
            for (int u = 0; u < 4; u++) {
                uint4 v = p[u];
                unsigned w0 = v.x, w1 = v.y, w2 = v.z, w3 = v.w;
                a[u*8+0] += bf2f((unsigned short)(w0 & 0xffff));
                a[u*8+1] += bf2f((unsigned short)(w0 >> 16));
                a[u*8+2] += bf2f((unsigned short)(w1 & 0xffff));
                a[u*8+3] += bf2f((unsigned short)(w1 >> 16));
                a[u*8+4] += bf2f((unsigned short)(w2 & 0xffff));
                a[u*8+5] += bf2f((unsigned short)(w2 >> 16));
                a[u*8+6] += bf2f((unsigned short)(w3 & 0xffff));
                a[u*8+7] += bf2f((unsigned short)(w3 >> 16));
            }
        }
        unsigned short* xp = (unsigned short*)&X2[row * 264 + cg * 32];
#pragma unroll
        for (int u = 0; u < 4; u++) {
            uint2 o;
            o.x = (unsigned)f2bf(a[u*8+0]*0.1f) | ((unsigned)f2bf(a[u*8+1]*0.1f) << 16);
            o.y = (unsigned)f2bf(a[u*8+2]*0.1f) | ((unsigned)f2bf(a[u*8+3]*0.1f) << 16);
            uint2 o2;
            o2.x = (unsigned)f2bf(a[u*8+4]*0.1f) | ((unsigned)f2bf(a[u*8+5]*0.1f) << 16);
            o2.y = (unsigned)f2bf(a[u*8+6]*0.1f) | ((unsigned)f2bf(a[u*8+7]*0.1f) << 16);
            *(uint2*)(xp + u * 8) = o;
            *(uint2*)(xp + u * 8 + 4) = o2;
        }
    }
    // first K-chunk's __syncthreads orders X2 writes before X2 reads (kc>=8)

    f4v acc[8];
    for (int f = 0; f < 8; f++) acc[f] = (f4v){0.f, 0.f, 0.f, 0.f};

    int w = tid >> 6, lane = tid & 63;
    int rowgrp = w & 1, nhalf = w >> 1;
    int quad = lane >> 4, l15 = lane & 15;

    for (int kc = 0; kc < 12; kc++) {
        int kb = kc * 64;
        int klocal = kb & 255;
        if (kc < 8) {   // A from global (hbf or x1); kc>=8 reads X2 LDS directly
            const unsigned short* asrc = (kb < 256) ? (const unsigned short*)hbf : x1;
            int row = tid >> 3, c8 = (tid & 7) * 8;
            uint4 v = *(const uint4*)(asrc + (m0 + row) * 256 + klocal + c8);
            *(uint4*)(&Al[row * 72 + c8]) = v;
        }
        {
            const unsigned short* bsrc = Wt + (kb >> 8) * 65536;
            int c8 = (tid & 7) * 8, rbase = tid >> 3;
            for (int r2 = 0; r2 < 8; r2++) {
                int n = r2 * 32 + rbase;
                uint4 v = *(const uint4*)(bsrc + n * 256 + klocal + c8);
                *(uint4*)(&Bl[n * 72 + c8]) = v;
            }
        }
        __syncthreads();
        for (int ks = 0; ks < 2; ks++) {
            s8v a;
            if (kc < 8)
                a = *(const s8v*)(&Al[(rowgrp * 16 + l15) * 72 + ks * 32 + quad * 8]);
            else
                a = *(const s8v*)(&X2[(rowgrp * 16 + l15) * 264 + klocal + ks * 32 + quad * 8]);
            for (int f = 0; f < 8; f++) {
                int n = nhalf * 128 + f * 16 + l15;
                s8v b = *(const s8v*)(&Bl[n * 72 + ks * 32 + quad * 8]);
                acc[f] = __builtin_amdgcn_mfma_f32_16x16x32_bf16(a, b, acc[f], 0, 0, 0);
            }
        }
        __syncthreads();
    }

    float py[4][3] = {};
    for (int f = 0; f < 8; f++) {
        int col = nhalf * 128 + f * 16 + l15;
        float cbv = cbl[col];
        float rw0 = rwl[col * 3], rw1 = rwl[col * 3 + 1], rw2 = rwl[col * 3 + 2];
        for (int r = 0; r < 4; r++) {
            int grow = m0 + rowgrp * 16 + quad * 4 + r;
            float cval = acc[f][r] + cbv;
            float hn = hdo[grow * 256 + col] + EPSC * tanhf(cval);
            hdo[grow * 256 + col] = hn;
            hbf[grow * 256 + col] = f2bf(hn);
            py[r][0] += hn * rw0; py[r][1] += hn * rw1; py[r][2] += hn * rw2;
        }
    }
    for (int off = 1; off < 16; off <<= 1)
        for (int r = 0; r < 4; r++)
            for (int j = 0; j < 3; j++)
                py[r][j] += __shfl_xor(py[r][j], off, 64);
    if (l15 == 0)
        for (int r = 0; r < 4; r++)
            for (int j = 0; j < 3; j++)
                yred[rowgrp][nhalf][quad][r][j] = py[r][j];
    __syncthreads();
    if (nhalf == 0 && l15 == 0) {
        for (int r = 0; r < 4; r++) {
            int grow = m0 + rowgrp * 16 + quad * 4 + r;
            for (int j = 0; j < 3; j++) {
                float yv = yred[rowgrp][0][quad][r][j] + yred[rowgrp][1][quad][r][j] + rb[j];
                yout[grow * 3 + j] = yv;
                if (yfin) yfin[grow * 3 + j] = yv;
            }
        }
    }
}

extern "C" void kernel_launch(void* const* d_in, const int* in_sizes, int n_in,
                              void* d_out, int out_size, void* d_ws, size_t ws_size,
                              hipStream_t stream) {
    const float* lm = (const float*)d_in[0];
    const float* ew = (const float*)d_in[1];
    const float* eb = (const float*)d_in[2];
    const float* rw = (const float*)d_in[3];
    const float* rb = (const float*)d_in[4];
    const float* cw = (const float*)d_in[5];
    const float* cb = (const float*)d_in[6];

    float* out = (float*)d_out;
    float* y_out = out;
    float* h_out = out + 24576;
    float* x_out = out + 24576 + 2097152;
    float* lp_out = x_out + 24576;

    char* ws = (char*)d_ws;
    int* nbr = (int*)ws;                       ws += NN * KNN * sizeof(int);
    float4* pos4 = (float4*)ws;                ws += NN * sizeof(float4);
    // union: segdj (kNN, 10.5 MB) aliases {hbf, x1, Wt} (sim, 8.4 MB)
    char* uni = ws;
    uint2* segdj = (uint2*)uni;
    unsigned short* hbf = (unsigned short*)uni;
    unsigned short* x1  = hbf + NN * DH;
    unsigned short* Wt  = x1 + NN * DH;

    prep_pos<<<NN / 256, 256, 0, stream>>>(lm, pos4);
    knn_scan<<<32 * NSEG, 256, 0, stream>>>(lm, pos4, segdj);
    knn_merge<<<NN / 256, 256, 0, stream>>>(segdj, nbr);
    prep_wt<<<768, 256, 0, stream>>>(cw, Wt);
    emb_kernel<<<NN, 256, 0, stream>>>(lm, ew, eb, rw, rb, h_out, hbf, x_out);
    for (int t = 0; t < TSTEPS; t++) {
        agg_kernel<<<NN / 4, 256, 0, stream>>>(hbf, x1, nbr);
        gemm_step<<<NN / 32, 256, 0, stream>>>(hbf, x1, nbr, Wt, cb, rw, rb, h_out,
                                               lp_out + t * 24576,
                                               (t == TSTEPS - 1) ? y_out : nullptr);
    }
}

// Round 4
// 548.484 us; speedup vs baseline: 1.2929x; 1.0391x over previous
//
#include <hip/hip_runtime.h>
#include <float.h>
#include <math.h>

#define NN 8192
#define DH 256
#define KNN 10
#define TSTEPS 10
#define EPSC 0.1f
#define NSEG 16
#define SEGSZ (NN / NSEG)   // 512

typedef short s8v __attribute__((ext_vector_type(8)));
typedef float f4v __attribute__((ext_vector_type(4)));

__device__ __forceinline__ float bf2f(unsigned short u) {
    union { unsigned u; float f; } c; c.u = ((unsigned)u) << 16; return c.f;
}
__device__ __forceinline__ unsigned short f2bf(float f) {
    union { float f; unsigned u; } c; c.f = f;
    unsigned r = c.u + 0x7FFF + ((c.u >> 16) & 1);
    return (unsigned short)(r >> 16);
}

// Top-10 state as NAMED SCALARS (b0..b9 / i0..i9) — guaranteed VGPR-resident,
// no arrays -> no scratch spill (R2 lesson: arrays went to private memory,
// 475 MB FETCH/dispatch). Rank-parallel insert, strict '<' (tie keeps earlier
// = lower index; candidates arrive in ascending index order).
#define DECL_TOP10 \
    float b0=FLT_MAX,b1=FLT_MAX,b2=FLT_MAX,b3=FLT_MAX,b4=FLT_MAX, \
          b5=FLT_MAX,b6=FLT_MAX,b7=FLT_MAX,b8=FLT_MAX,b9=FLT_MAX; \
    int   i0=-1,i1=-1,i2=-1,i3=-1,i4=-1,i5=-1,i6=-1,i7=-1,i8=-1,i9=-1;

#define INS10(dv, jv) do { \
    float _d = (dv); int _j = (jv); \
    bool c0=_d<b0, c1=_d<b1, c2=_d<b2, c3=_d<b3, c4=_d<b4; \
    bool c5=_d<b5, c6=_d<b6, c7=_d<b7, c8=_d<b8, c9=_d<b9; \
    b9 = c9 ? (c8 ? b8 : _d) : b9;  i9 = c9 ? (c8 ? i8 : _j) : i9; \
    b8 = c8 ? (c7 ? b7 : _d) : b8;  i8 = c8 ? (c7 ? i7 : _j) : i8; \
    b7 = c7 ? (c6 ? b6 : _d) : b7;  i7 = c7 ? (c6 ? i6 : _j) : i7; \
    b6 = c6 ? (c5 ? b5 : _d) : b6;  i6 = c6 ? (c5 ? i5 : _j) : i6; \
    b5 = c5 ? (c4 ? b4 : _d) : b5;  i5 = c5 ? (c4 ? i4 : _j) : i5; \
    b4 = c4 ? (c3 ? b3 : _d) : b4;  i4 = c4 ? (c3 ? i3 : _j) : i4; \
    b3 = c3 ? (c2 ? b2 : _d) : b3;  i3 = c3 ? (c2 ? i2 : _j) : i3; \
    b2 = c2 ? (c1 ? b1 : _d) : b2;  i2 = c2 ? (c1 ? i1 : _j) : i2; \
    b1 = c1 ? (c0 ? b0 : _d) : b1;  i1 = c1 ? (c0 ? i0 : _j) : i1; \
    b0 = c0 ? _d : b0;              i0 = c0 ? _j : i0; \
} while (0)

// ---------------- conv_ws [3][256][256] (k,n) -> bf16 Wt [3][n][k] ------------
__global__ void prep_wt(const float* __restrict__ W, unsigned short* __restrict__ Wt) {
    int e = blockIdx.x * 256 + threadIdx.x;
    int g = e >> 16; int rem = e & 65535;
    int n = rem >> 8; int k = rem & 255;
    Wt[e] = f2bf(W[g * 65536 + k * 256 + n]);
}

// ---------------- pos4[j] = {x, y, z, |p|^2} ----------------------------------
__global__ void prep_pos(const float* __restrict__ pos, float4* __restrict__ pos4) {
    int j = blockIdx.x * 256 + threadIdx.x;
    float x = pos[j * 3], y = pos[j * 3 + 1], z = pos[j * 3 + 2];
    float4 v; v.x = x; v.y = y; v.z = z; v.w = x * x + y * y + z * z;
    pos4[j] = v;
}

// ---------------- kNN pass 1: per-(query, segment) top-10 ---------------------
__launch_bounds__(256)
__global__ void knn_scan(const float* __restrict__ pos, const float4* __restrict__ pos4,
                         uint2* __restrict__ segdj) {
    __shared__ float4 cand[SEGSZ];
    int qb = blockIdx.x >> 4, seg = blockIdx.x & 15;
    int tid = threadIdx.x;
    int i = qb * 256 + tid;
    for (int t = tid; t < SEGSZ; t += 256) cand[t] = pos4[seg * SEGSZ + t];
    float xi = pos[i * 3], yi = pos[i * 3 + 1], zi = pos[i * 3 + 2];
    float sqi = xi * xi + yi * yi + zi * zi;
    __syncthreads();

    DECL_TOP10;
    int jbase = seg * SEGSZ;
#pragma unroll 4
    for (int t = 0; t < SEGSZ; t++) {
        float4 c = cand[t];
        float m = c.x * xi + c.y * yi + c.z * zi;
        float d = (sqi + c.w) - 2.0f * m;
        int j = jbase + t;
        if (j == i) d = FLT_MAX;          // cmp+cndmask, branchless
        INS10(d, j);
    }
    uint2* op = segdj + (seg * NN + i) * KNN;
    op[0] = make_uint2(__float_as_uint(b0), (unsigned)i0);
    op[1] = make_uint2(__float_as_uint(b1), (unsigned)i1);
    op[2] = make_uint2(__float_as_uint(b2), (unsigned)i2);
    op[3] = make_uint2(__float_as_uint(b3), (unsigned)i3);
    op[4] = make_uint2(__float_as_uint(b4), (unsigned)i4);
    op[5] = make_uint2(__float_as_uint(b5), (unsigned)i5);
    op[6] = make_uint2(__float_as_uint(b6), (unsigned)i6);
    op[7] = make_uint2(__float_as_uint(b7), (unsigned)i7);
    op[8] = make_uint2(__float_as_uint(b8), (unsigned)i8);
    op[9] = make_uint2(__float_as_uint(b9), (unsigned)i9);
}

// ---------------- kNN pass 2: merge 16 sorted lists -> final top-10 -----------
__global__ void knn_merge(const uint2* __restrict__ segdj, int* __restrict__ nbr) {
    int i = blockIdx.x * 256 + threadIdx.x;
    DECL_TOP10;
    for (int s = 0; s < NSEG; s++) {       // ascending seg = ascending index on ties
        const uint2* p = segdj + (s * NN + i) * KNN;
#pragma unroll
        for (int q = 0; q < KNN; q++) {
            uint2 v = p[q];
            INS10(__uint_as_float(v.x), (int)v.y);
        }
    }
    int* np = nbr + i * KNN;
    np[0] = i0; np[1] = i1; np[2] = i2; np[3] = i3; np[4] = i4;
    np[5] = i5; np[6] = i6; np[7] = i7; np[8] = i8; np[9] = i9;
}

// ---------------- h = lm@emb_w + emb_b ; x = h@rw + rb ------------------------
__global__ void emb_kernel(const float* __restrict__ lm, const float* __restrict__ ew,
                           const float* __restrict__ eb, const float* __restrict__ rw,
                           const float* __restrict__ rb,
                           float* __restrict__ hdo, unsigned short* __restrict__ hbf,
                           float* __restrict__ xout) {
    __shared__ float s0[4], s1[4], s2[4];
    int i = blockIdx.x, d = threadIdx.x;
    float a0 = lm[i * 3], a1 = lm[i * 3 + 1], a2 = lm[i * 3 + 2];
    float h = eb[d] + a0 * ew[d] + a1 * ew[256 + d] + a2 * ew[512 + d];
    hdo[i * 256 + d] = h;
    hbf[i * 256 + d] = f2bf(h);
    float p0 = h * rw[d * 3], p1 = h * rw[d * 3 + 1], p2 = h * rw[d * 3 + 2];
    for (int off = 32; off; off >>= 1) {
        p0 += __shfl_down(p0, off, 64);
        p1 += __shfl_down(p1, off, 64);
        p2 += __shfl_down(p2, off, 64);
    }
    int lane = d & 63, wid = d >> 6;
    if (lane == 0) { s0[wid] = p0; s1[wid] = p1; s2[wid] = p2; }
    __syncthreads();
    if (d == 0) {
        xout[i * 3 + 0] = s0[0] + s0[1] + s0[2] + s0[3] + rb[0];
        xout[i * 3 + 1] = s1[0] + s1[1] + s1[2] + s1[3] + rb[1];
        xout[i * 3 + 2] = s2[0] + s2[1] + s2[2] + s2[3] + rb[2];
    }
}

// ---------------- hop-1: x1[i] = 0.1 * sum_{j in nbr(i)} hbf[j] ---------------
__global__ void agg_kernel(const unsigned short* __restrict__ src,
                           unsigned short* __restrict__ dst,
                           const int* __restrict__ nbr) {
    int tid = threadIdx.x;
    int wid = tid >> 6, lane = tid & 63;
    int node = blockIdx.x * 4 + wid;
    int d0 = lane * 4;
    float a0 = 0.f, a1 = 0.f, a2 = 0.f, a3 = 0.f;
    const int* nb = nbr + node * KNN;
    for (int q = 0; q < KNN; q++) {
        int j = nb[q];
        uint2 v = *(const uint2*)(src + j * 256 + d0);
        a0 += bf2f((unsigned short)(v.x & 0xffff));
        a1 += bf2f((unsigned short)(v.x >> 16));
        a2 += bf2f((unsigned short)(v.y & 0xffff));
        a3 += bf2f((unsigned short)(v.y >> 16));
    }
    uint2 o;
    o.x = (unsigned)f2bf(a0 * 0.1f) | ((unsigned)f2bf(a1 * 0.1f) << 16);
    o.y = (unsigned)f2bf(a2 * 0.1f) | ((unsigned)f2bf(a3 * 0.1f) << 16);
    *(uint2*)(dst + node * 256 + d0) = o;
}

// ------- fused: hop-2 gather (x2 tile in LDS) + GEMM + Euler + readout --------
__launch_bounds__(256)
__global__ void gemm_step(unsigned short* hbf,
                          const unsigned short* __restrict__ x1,
                          const int* __restrict__ nbr,
                          const unsigned short* __restrict__ Wt,
                          const float* __restrict__ cb,
                          const float* __restrict__ rw, const float* __restrict__ rb,
                          float* hdo, float* __restrict__ yout, float* yfin) {
    __shared__ __align__(16) short Al[32 * 72];
    __shared__ __align__(16) short Bl[256 * 72];
    __shared__ __align__(16) short X2[32 * 264];
    __shared__ float rwl[768];
    __shared__ float cbl[256];
    __shared__ float yred[2][2][4][4][3];

    int tid = threadIdx.x;
    int m0 = blockIdx.x * 32;
    for (int idx = tid; idx < 768; idx += 256) rwl[idx] = rw[idx];
    cbl[tid] = cb[tid];

    // ---- fused hop-2 aggregation: X2[row][:] = bf16(0.1 * sum x1[nbr[row]]) ----
    {
        int row = tid >> 3, cg = tid & 7;
        const int* nb = nbr + (m0 + row) * KNN;
        float a[32];
#pragma unroll
        for (int e = 0; e < 32; e++) a[e] = 0.f;
        for (int q = 0; q < KNN; q++) {
            int j = nb[q];
            const uint4* p = (const uint4*)(x1 + j * 256 + cg * 32);
#pragma unroll
            for (int u = 0; u < 4; u++) {
                uint4 v = p[u];
                unsigned w0 = v.x, w1 = v.y, w2 = v.z, w3 = v.w;
                a[u*8+0] += bf2f((unsigned short)(w0 & 0xffff));
                a[u*8+1] += bf2f((unsigned short)(w0 >> 16));
                a[u*8+2] += bf2f((unsigned short)(w1 & 0xffff));
                a[u*8+3] += bf2f((unsigned short)(w1 >> 16));
                a[u*8+4] += bf2f((unsigned short)(w2 & 0xffff));
                a[u*8+5] += bf2f((unsigned short)(w2 >> 16));
                a[u*8+6] += bf2f((unsigned short)(w3 & 0xffff));
                a[u*8+7] += bf2f((unsigned short)(w3 >> 16));
            }
        }
        unsigned short* xp = (unsigned short*)&X2[row * 264 + cg * 32];
#pragma unroll
        for (int u = 0; u < 4; u++) {
            uint2 o;
            o.x = (unsigned)f2bf(a[u*8+0]*0.1f) | ((unsigned)f2bf(a[u*8+1]*0.1f) << 16);
            o.y = (unsigned)f2bf(a[u*8+2]*0.1f) | ((unsigned)f2bf(a[u*8+3]*0.1f) << 16);
            uint2 o2;
            o2.x = (unsigned)f2bf(a[u*8+4]*0.1f) | ((unsigned)f2bf(a[u*8+5]*0.1f) << 16);
            o2.y = (unsigned)f2bf(a[u*8+6]*0.1f) | ((unsigned)f2bf(a[u*8+7]*0.1f) << 16);
            *(uint2*)(xp + u * 8) = o;
            *(uint2*)(xp + u * 8 + 4) = o2;
        }
    }

    f4v acc[8];
    for (int f = 0; f < 8; f++) acc[f] = (f4v){0.f, 0.f, 0.f, 0.f};

    int w = tid >> 6, lane = tid & 63;
    int rowgrp = w & 1, nhalf = w >> 1;
    int quad = lane >> 4, l15 = lane & 15;

    for (int kc = 0; kc < 12; kc++) {
        int kb = kc * 64;
        int klocal = kb & 255;
        if (kc < 8) {
            const unsigned short* asrc = (kb < 256) ? (const unsigned short*)hbf : x1;
            int row = tid >> 3, c8 = (tid & 7) * 8;
            uint4 v = *(const uint4*)(asrc + (m0 + row) * 256 + klocal + c8);
            *(uint4*)(&Al[row * 72 + c8]) = v;
        }
        {
            const unsigned short* bsrc = Wt + (kb >> 8) * 65536;
            int c8 = (tid & 7) * 8, rbase = tid >> 3;
            for (int r2 = 0; r2 < 8; r2++) {
                int n = r2 * 32 + rbase;
                uint4 v = *(const uint4*)(bsrc + n * 256 + klocal + c8);
                *(uint4*)(&Bl[n * 72 + c8]) = v;
            }
        }
        __syncthreads();
        for (int ks = 0; ks < 2; ks++) {
            s8v a;
            if (kc < 8)
                a = *(const s8v*)(&Al[(rowgrp * 16 + l15) * 72 + ks * 32 + quad * 8]);
            else
                a = *(const s8v*)(&X2[(rowgrp * 16 + l15) * 264 + klocal + ks * 32 + quad * 8]);
            for (int f = 0; f < 8; f++) {
                int n = nhalf * 128 + f * 16 + l15;
                s8v b = *(const s8v*)(&Bl[n * 72 + ks * 32 + quad * 8]);
                acc[f] = __builtin_amdgcn_mfma_f32_16x16x32_bf16(a, b, acc[f], 0, 0, 0);
            }
        }
        __syncthreads();
    }

    float py[4][3] = {};
    for (int f = 0; f < 8; f++) {
        int col = nhalf * 128 + f * 16 + l15;
        float cbv = cbl[col];
        float rw0 = rwl[col * 3], rw1 = rwl[col * 3 + 1], rw2 = rwl[col * 3 + 2];
        for (int r = 0; r < 4; r++) {
            int grow = m0 + rowgrp * 16 + quad * 4 + r;
            float cval = acc[f][r] + cbv;
            float hn = hdo[grow * 256 + col] + EPSC * tanhf(cval);
            hdo[grow * 256 + col] = hn;
            hbf[grow * 256 + col] = f2bf(hn);
            py[r][0] += hn * rw0; py[r][1] += hn * rw1; py[r][2] += hn * rw2;
        }
    }
    for (int off = 1; off < 16; off <<= 1)
        for (int r = 0; r < 4; r++)
            for (int j = 0; j < 3; j++)
                py[r][j] += __shfl_xor(py[r][j], off, 64);
    if (l15 == 0)
        for (int r = 0; r < 4; r++)
            for (int j = 0; j < 3; j++)
                yred[rowgrp][nhalf][quad][r][j] = py[r][j];
    __syncthreads();
    if (nhalf == 0 && l15 == 0) {
        for (int r = 0; r < 4; r++) {
            int grow = m0 + rowgrp * 16 + quad * 4 + r;
            for (int j = 0; j < 3; j++) {
                float yv = yred[rowgrp][0][quad][r][j] + yred[rowgrp][1][quad][r][j] + rb[j];
                yout[grow * 3 + j] = yv;
                if (yfin) yfin[grow * 3 + j] = yv;
            }
        }
    }
}

extern "C" void kernel_launch(void* const* d_in, const int* in_sizes, int n_in,
                              void* d_out, int out_size, void* d_ws, size_t ws_size,
                              hipStream_t stream) {
    const float* lm = (const float*)d_in[0];
    const float* ew = (const float*)d_in[1];
    const float* eb = (const float*)d_in[2];
    const float* rw = (const float*)d_in[3];
    const float* rb = (const float*)d_in[4];
    const float* cw = (const float*)d_in[5];
    const float* cb = (const float*)d_in[6];

    float* out = (float*)d_out;
    float* y_out = out;
    float* h_out = out + 24576;
    float* x_out = out + 24576 + 2097152;
    float* lp_out = x_out + 24576;

    char* ws = (char*)d_ws;
    int* nbr = (int*)ws;                       ws += NN * KNN * sizeof(int);
    float4* pos4 = (float4*)ws;                ws += NN * sizeof(float4);
    char* uni = ws;
    uint2* segdj = (uint2*)uni;
    unsigned short* hbf = (unsigned short*)uni;
    unsigned short* x1  = hbf + NN * DH;
    unsigned short* Wt  = x1 + NN * DH;

    prep_pos<<<NN / 256, 256, 0, stream>>>(lm, pos4);
    knn_scan<<<32 * NSEG, 256, 0, stream>>>(lm, pos4, segdj);
    knn_merge<<<NN / 256, 256, 0, stream>>>(segdj, nbr);
    prep_wt<<<768, 256, 0, stream>>>(cw, Wt);
    emb_kernel<<<NN, 256, 0, stream>>>(lm, ew, eb, rw, rb, h_out, hbf, x_out);
    for (int t = 0; t < TSTEPS; t++) {
        agg_kernel<<<NN / 4, 256, 0, stream>>>(hbf, x1, nbr);
        gemm_step<<<NN / 32, 256, 0, stream>>>(hbf, x1, nbr, Wt, cb, rw, rb, h_out,
                                               lp_out + t * 24576,
                                               (t == TSTEPS - 1) ? y_out : nullptr);
    }
}